// Round 12
// baseline (391.342 us; speedup 1.0000x reference)
//
#include <hip/hip_runtime.h>
#include <hip/hip_fp16.h>

#define N_NODES 100000
#define N_EDGES 1600000
#define D 64
#define N16 (N_NODES * 16)      // elements per 16-feature slice plane

#define NB 256                  // fat buckets
#define BUCKET_W 391            // nodes per bucket (256*391 = 100096 >= 100000)
#define NB_USED ((N_NODES + BUCKET_W - 1) / BUCKET_W)   // 256
#define NBLK 256                // partition blocks (exact per-block regions)
#define CHUNK ((N_EDGES + NBLK - 1) / NBLK)             // 6250
#define CCAP 7168               // max edges per bucket (mean 6250, sd ~79)
#define LMASK 511               // 9-bit local node index

// ---------------- pass A: per-block LDS histogram -> gcount[b*NBLK+blk] ----------------
__global__ __launch_bounds__(256) void bucket_count(const int* __restrict__ dst,
                                                    int* __restrict__ gcount) {
    __shared__ int h[NB];
    if (threadIdx.x < NB) h[threadIdx.x] = 0;
    __syncthreads();
    const int blk = blockIdx.x;
    const int beg = blk * CHUNK;
    const int end = min(beg + CHUNK, N_EDGES);
    for (int e = beg + threadIdx.x; e < end; e += 256)
        atomicAdd(&h[dst[e] / BUCKET_W], 1);
    __syncthreads();
    if (threadIdx.x < NB)
        gcount[threadIdx.x * NBLK + blk] = h[threadIdx.x];   // exact, no global atomics
}

// ---------------- exact scan of 65536 (bucket,block) counts -> subbase ----------------
__global__ __launch_bounds__(1024) void scan64k(const int* __restrict__ gcount,
                                                int* __restrict__ subbase) {
    __shared__ int s[1024];
    const int t = threadIdx.x;
    int loc[64];
    int sum = 0;
#pragma unroll
    for (int i = 0; i < 64; ++i) { loc[i] = gcount[t * 64 + i]; sum += loc[i]; }
    s[t] = sum;
    __syncthreads();
    for (int off = 1; off < 1024; off <<= 1) {
        int u = (t >= off) ? s[t - off] : 0;
        __syncthreads();
        s[t] += u;
        __syncthreads();
    }
    int excl = s[t] - sum;
#pragma unroll
    for (int i = 0; i < 64; ++i) { subbase[t * 64 + i] = excl; excl += loc[i]; }
    if (t == 1023) subbase[NB * NBLK] = excl;   // == N_EDGES
}

// ---------------- pass B: partition with LDS cursors (no global atomics) ----------------
__global__ __launch_bounds__(256) void partition_edges(const int* __restrict__ src,
                                                       const int* __restrict__ dst,
                                                       const int* __restrict__ subbase,
                                                       int* __restrict__ part) {
    __shared__ int cur[NB];
    const int blk = blockIdx.x;
    if (threadIdx.x < NB) cur[threadIdx.x] = subbase[threadIdx.x * NBLK + blk];
    __syncthreads();
    const int beg = blk * CHUNK;
    const int end = min(beg + CHUNK, N_EDGES);
    for (int e = beg + threadIdx.x; e < end; e += 256) {
        const int d = dst[e];
        const int s = src[e];
        const int b = d / BUCKET_W;
        const int pos = atomicAdd(&cur[b], 1);          // LDS atomic
        part[pos] = (s << 9) | (d - b * BUCKET_W);      // ~24 edges/region: lines fill
    }
}

// ---------------- pass C: per-bucket counting sort -> col, rowptr, dinv ----------------
__global__ __launch_bounds__(256) void bucket_csr(const int* __restrict__ subbase,
                                                  const int* __restrict__ part,
                                                  int* __restrict__ col,
                                                  int* __restrict__ rowptr,
                                                  float* __restrict__ dinv) {
    __shared__ int ed[CCAP];
    __shared__ int hist[BUCKET_W];
    __shared__ int offs[BUCKET_W];
    __shared__ int lcur[BUCKET_W];
    const int b = blockIdx.x;
    const int base = subbase[b * NBLK];
    const int cnt = min(subbase[(b + 1) * NBLK] - base, CCAP);
    const int n0 = b * BUCKET_W;
    const int nn = min(N_NODES - n0, BUCKET_W);
    const int t = threadIdx.x;

    for (int i = t; i < BUCKET_W; i += 256) hist[i] = 0;
    for (int i = t; i < cnt; i += 256) ed[i] = part[base + i];
    __syncthreads();
    for (int i = t; i < cnt; i += 256) atomicAdd(&hist[ed[i] & LMASK], 1);
    __syncthreads();
    if (t == 0) {
        int a = 0;
        for (int i = 0; i < nn; ++i) { offs[i] = a; lcur[i] = a; a += hist[i]; }
    }
    __syncthreads();
    for (int i = t; i < nn; i += 256) {
        rowptr[n0 + i] = base + offs[i];
        dinv[n0 + i] = rsqrtf((float)hist[i] + 1.0f);
    }
    if (b == NB_USED - 1 && t == 0) rowptr[N_NODES] = N_EDGES;
    __syncthreads();
    for (int i = t; i < cnt; i += 256) {
        const int p = ed[i];
        const int pos = atomicAdd(&lcur[p & LMASK], 1);
        col[base + pos] = p >> 9;
    }
}

// ---------------- xq[q][n][f] = (half)(x[n][q*16+f] * dinv[n])  [slice-major fp16] -----
__global__ void convert_scale(const float* __restrict__ x, const float* __restrict__ dinv,
                              __half* __restrict__ xq) {
    int t = blockIdx.x * blockDim.x + threadIdx.x;
    if (t >= N_NODES * 8) return;
    const int node = t >> 3, oct = t & 7;       // oct: 8 features
    const int q = oct >> 1, half = oct & 1;
    const float dv = dinv[node];
    const float2* xr = (const float2*)(x + (size_t)node * 64 + oct * 8);
    __half2* xw = (__half2*)(xq + (size_t)q * N16 + (size_t)node * 16 + half * 8);
#pragma unroll
    for (int i = 0; i < 4; ++i) {
        const float2 v = xr[i];
        xw[i] = __floats2half2_rn(v.x * dv, v.y * dv);
    }
}

// ---------------- sliced aggregation: agg[q][d][f] = dv*(sum xq[q][s][f] + xq[q][d][f]) -
// blockIdx&7 = XCD id g; slice q = g&3 -> each XCD gathers from ONE 3.2MB plane
// (L2-resident). Wave = (node, q); lanes = 4 edge-slots x 16 features.
__global__ __launch_bounds__(256) void agg_slice4(const __half* __restrict__ xq,
                                                  const int* __restrict__ rowptr,
                                                  const int* __restrict__ col,
                                                  const float* __restrict__ dinv,
                                                  float* __restrict__ agg) {
    const int g = blockIdx.x & 7;
    const int nb = blockIdx.x >> 3;
    const int q = g & 3;
    const int hi = g >> 2;
    const int nd = nb * 8 + hi * 4 + (threadIdx.x >> 6);   // N_NODES % 8 == 0
    const int lane = threadIdx.x & 63;
    const int e4 = lane >> 4;   // edge slot 0..3
    const int f  = lane & 15;   // feature within slice

    const __half* xs = xq + (size_t)q * N16;
    const int beg = rowptr[nd];
    const int end = rowptr[nd + 1];

    float a0 = 0.f, a1 = 0.f, a2 = 0.f, a3 = 0.f;
    int j = beg;
    for (; j + 15 < end; j += 16) {
        const int s0 = col[j + e4];           // 16B col window: 1 line, L1/L2-hit
        const int s1 = col[j + 4 + e4];
        const int s2 = col[j + 8 + e4];
        const int s3 = col[j + 12 + e4];
        a0 += __half2float(xs[(size_t)s0 * 16 + f]);   // 32B row-slice: L2-resident
        a1 += __half2float(xs[(size_t)s1 * 16 + f]);
        a2 += __half2float(xs[(size_t)s2 * 16 + f]);
        a3 += __half2float(xs[(size_t)s3 * 16 + f]);
    }
    for (; j < end; j += 4) {
        const int idx = j + e4;
        if (idx < end) {
            const int s0 = col[idx];
            a0 += __half2float(xs[(size_t)s0 * 16 + f]);
        }
    }
    float a = (a0 + a1) + (a2 + a3);
    a += __shfl_xor(a, 16, 64);
    a += __shfl_xor(a, 32, 64);
    if (e4 == 0) {
        const float dv = dinv[nd];
        const float self = __half2float(xs[(size_t)nd * 16 + f]);  // self UNSCALED in sum
        agg[(size_t)q * N16 + (size_t)nd * 16 + f] = dv * (a + self);
    }
}

// ---------------- GEMM: r = relu(agg @ W + b); write fp32 or scaled-fp16 slice-major ----
__device__ __forceinline__ float rlane_ff(float v, int l) {
    return __int_as_float(__builtin_amdgcn_readlane(__float_as_int(v), l));
}

template <bool SCALED_HALF_OUT>
__global__ __launch_bounds__(256) void gemm64(const float* __restrict__ aggs,
                                              const float* __restrict__ W,
                                              const float* __restrict__ bias,
                                              const float* __restrict__ dinv,
                                              float* __restrict__ out,
                                              __half* __restrict__ outh, int n) {
    const int lane = threadIdx.x & 63;
    const int gwave = (blockIdx.x * blockDim.x + threadIdx.x) >> 6;
    const int nwaves = (gridDim.x * blockDim.x) >> 6;
    float wcol[64];
#pragma unroll
    for (int k = 0; k < 64; ++k) wcol[k] = W[k * 64 + lane];
    const float bv = bias[lane];
    const int q = lane >> 4, f = lane & 15;     // feature = q*16+f == lane
    const float* ap = aggs + (size_t)q * N16 + f;

    for (int nd = gwave; nd < n; nd += nwaves) {
        const float a = ap[(size_t)nd * 16];
        float g0 = 0.f, g1 = 0.f, g2 = 0.f, g3 = 0.f;
#pragma unroll
        for (int k = 0; k < 64; k += 4) {
            g0 = fmaf(rlane_ff(a, k + 0), wcol[k + 0], g0);
            g1 = fmaf(rlane_ff(a, k + 1), wcol[k + 1], g1);
            g2 = fmaf(rlane_ff(a, k + 2), wcol[k + 2], g2);
            g3 = fmaf(rlane_ff(a, k + 3), wcol[k + 3], g3);
        }
        const float r = fmaxf((g0 + g1) + (g2 + g3) + bv, 0.f);
        if (SCALED_HALF_OUT)
            outh[(size_t)q * N16 + (size_t)nd * 16 + f] = __float2half(r * dinv[nd]);
        else
            out[(size_t)nd * 64 + lane] = r;
    }
}

extern "C" void kernel_launch(void* const* d_in, const int* in_sizes, int n_in,
                              void* d_out, int out_size, void* d_ws, size_t ws_size,
                              hipStream_t stream) {
    const float* feature = (const float*)d_in[0];
    const int*   edges   = (const int*)d_in[1];   // [2, E] flat: src then dst
    const float* W1      = (const float*)d_in[2];
    const float* b1      = (const float*)d_in[3];
    const float* W2      = (const float*)d_in[4];
    const float* b2      = (const float*)d_in[5];
    float* out = (float*)d_out;

    const int* src = edges;
    const int* dst = edges + N_EDGES;

    // workspace layout
    char* w = (char*)d_ws;
    int*    gcount  = (int*)w;    w += sizeof(int) * (NB * NBLK);       // 65536
    int*    subbase = (int*)w;    w += sizeof(int) * (NB * NBLK + 1);   // 65537
    int*    rowptr  = (int*)w;    w += sizeof(int) * (N_NODES + 1);
    float*  dinv    = (float*)w;  w += sizeof(float) * (N_NODES);
    int*    part    = (int*)w;    w += sizeof(int) * (N_EDGES);          // 6.4MB
    int*    colA    = (int*)w;    w += sizeof(int) * (N_EDGES);          // 6.4MB
    __half* xq      = (__half*)w; w += sizeof(__half) * ((size_t)4 * N16);  // 12.8MB
    __half* y1q     = (__half*)w; w += sizeof(__half) * ((size_t)4 * N16);  // 12.8MB
    float*  aggsA   = (float*)w;  w += sizeof(float) * ((size_t)4 * N16);   // 25.6MB

    // ---- partition + CSR + scaled-fp16 slice-major features (once) ----
    bucket_count<<<NBLK, 256, 0, stream>>>(dst, gcount);
    scan64k<<<1, 1024, 0, stream>>>(gcount, subbase);
    partition_edges<<<NBLK, 256, 0, stream>>>(src, dst, subbase, part);
    bucket_csr<<<NB_USED, 256, 0, stream>>>(subbase, part, colA, rowptr, dinv);
    convert_scale<<<(N_NODES * 8 + 255) / 256, 256, 0, stream>>>(feature, dinv, xq);

    const int agg_grid = (N_NODES / 8) * 8;   // 12500 node-groups x 8 (XCD,slice) blocks

    // ---- layer 1 ----
    agg_slice4<<<agg_grid, 256, 0, stream>>>(xq, rowptr, colA, dinv, aggsA);
    gemm64<true><<<2048, 256, 0, stream>>>(aggsA, W1, b1, dinv, nullptr, y1q, N_NODES);

    // ---- layer 2 ----
    agg_slice4<<<agg_grid, 256, 0, stream>>>(y1q, rowptr, colA, dinv, aggsA);
    gemm64<false><<<2048, 256, 0, stream>>>(aggsA, W2, b2, dinv, out, nullptr, N_NODES);
}

// Round 13
// 360.227 us; speedup vs baseline: 1.0864x; 1.0864x over previous
//
#include <hip/hip_runtime.h>
#include <hip/hip_fp16.h>

#define N_NODES 100000
#define N_EDGES 1600000
#define D 64
#define NPART 4
#define PART_W 25000            // src nodes per partition: 25000*128B = 3.2MB < 4MB XCD-L2

#define NB 256                  // fat buckets
#define BUCKET_W 391            // nodes per bucket (256*391 = 100096 >= 100000)
#define NB_USED 256
#define NBLK 256                // partition blocks (exact per-block regions)
#define CHUNK ((N_EDGES + NBLK - 1) / NBLK)             // 6250
#define CCAP 7168               // max edges per bucket (mean 6250, sd ~79)
#define LMASK 511               // 9-bit local node index
#define KMAX (BUCKET_W * 4)     // 1564 sort keys (local, src_range)

// ---------------- pass A: per-block LDS histogram -> gcount[b*NBLK+blk] ----------------
__global__ __launch_bounds__(256) void bucket_count(const int* __restrict__ dst,
                                                    int* __restrict__ gcount) {
    __shared__ int h[NB];
    if (threadIdx.x < NB) h[threadIdx.x] = 0;
    __syncthreads();
    const int blk = blockIdx.x;
    const int beg = blk * CHUNK;
    const int end = min(beg + CHUNK, N_EDGES);
    for (int e = beg + threadIdx.x; e < end; e += 256)
        atomicAdd(&h[dst[e] / BUCKET_W], 1);
    __syncthreads();
    if (threadIdx.x < NB)
        gcount[threadIdx.x * NBLK + blk] = h[threadIdx.x];   // exact, no global atomics
}

// ---------------- exact scan of 65536 (bucket,block) counts -> subbase ----------------
__global__ __launch_bounds__(1024) void scan64k(const int* __restrict__ gcount,
                                                int* __restrict__ subbase) {
    __shared__ int s[1024];
    const int t = threadIdx.x;
    int loc[64];
    int sum = 0;
#pragma unroll
    for (int i = 0; i < 64; ++i) { loc[i] = gcount[t * 64 + i]; sum += loc[i]; }
    s[t] = sum;
    __syncthreads();
    for (int off = 1; off < 1024; off <<= 1) {
        int u = (t >= off) ? s[t - off] : 0;
        __syncthreads();
        s[t] += u;
        __syncthreads();
    }
    int excl = s[t] - sum;
#pragma unroll
    for (int i = 0; i < 64; ++i) { subbase[t * 64 + i] = excl; excl += loc[i]; }
    if (t == 1023) subbase[NB * NBLK] = excl;   // == N_EDGES
}

// ---------------- pass B: partition with LDS cursors (no global atomics) ----------------
__global__ __launch_bounds__(256) void partition_edges(const int* __restrict__ src,
                                                       const int* __restrict__ dst,
                                                       const int* __restrict__ subbase,
                                                       int* __restrict__ part) {
    __shared__ int cur[NB];
    const int blk = blockIdx.x;
    if (threadIdx.x < NB) cur[threadIdx.x] = subbase[threadIdx.x * NBLK + blk];
    __syncthreads();
    const int beg = blk * CHUNK;
    const int end = min(beg + CHUNK, N_EDGES);
    for (int e = beg + threadIdx.x; e < end; e += 256) {
        const int d = dst[e];
        const int s = src[e];
        const int b = d / BUCKET_W;
        const int pos = atomicAdd(&cur[b], 1);          // LDS atomic
        part[pos] = (s << 9) | (d - b * BUCKET_W);
    }
}

// ---------------- pass C: per-bucket sort by (local,dst-range) -> col, rowptr4, dinv ----
__global__ __launch_bounds__(256) void bucket_csr(const int* __restrict__ subbase,
                                                  const int* __restrict__ part,
                                                  int* __restrict__ col,
                                                  int* __restrict__ rowptr4,
                                                  float* __restrict__ dinv) {
    __shared__ int ed[CCAP];
    __shared__ int hist[KMAX];
    __shared__ int bs[256];
    const int b = blockIdx.x;
    const int base = subbase[b * NBLK];
    const int cnt = min(subbase[(b + 1) * NBLK] - base, CCAP);
    const int n0 = b * BUCKET_W;
    const int nn = min(N_NODES - n0, BUCKET_W);
    const int nk = nn * 4;
    const int t = threadIdx.x;

    for (int i = t; i < KMAX; i += 256) hist[i] = 0;
    for (int i = t; i < cnt; i += 256) ed[i] = part[base + i];
    __syncthreads();
    for (int i = t; i < cnt; i += 256) {
        const int p = ed[i];
        const int key = ((p & LMASK) << 2) | ((p >> 9) / PART_W);
        atomicAdd(&hist[key], 1);
    }
    __syncthreads();
    // dinv from per-node 4-bin sums (before hist is overwritten by the scan)
    for (int i = t; i < nn; i += 256) {
        const int deg = hist[4 * i] + hist[4 * i + 1] + hist[4 * i + 2] + hist[4 * i + 3];
        dinv[n0 + i] = rsqrtf((float)deg + 1.0f);
    }
    // parallel exclusive scan over KMAX bins, 7 per thread (in-place)
    int loc[7];
    int lsum = 0;
#pragma unroll
    for (int i = 0; i < 7; ++i) {
        const int key = t * 7 + i;
        loc[i] = (key < KMAX) ? hist[key] : 0;
        lsum += loc[i];
    }
    bs[t] = lsum;
    __syncthreads();
    for (int off = 1; off < 256; off <<= 1) {
        int u = (t >= off) ? bs[t - off] : 0;
        __syncthreads();
        bs[t] += u;
        __syncthreads();
    }
    int run = bs[t] - lsum;
#pragma unroll
    for (int i = 0; i < 7; ++i) {
        const int key = t * 7 + i;
        if (key < KMAX) hist[key] = run;
        run += loc[i];
    }
    __syncthreads();
    // rowptr4[(n0+i)*4+k] = base + start  (contiguous in key)
    for (int key = t; key < nk; key += 256) rowptr4[n0 * 4 + key] = base + hist[key];
    if (b == NB_USED - 1 && t == 0) rowptr4[4 * N_NODES] = N_EDGES;
    __syncthreads();
    // scatter (atomicAdd destroys hist, rowptr4 already saved)
    for (int i = t; i < cnt; i += 256) {
        const int p = ed[i];
        const int s = p >> 9;
        const int key = ((p & LMASK) << 2) | (s / PART_W);
        const int pos = atomicAdd(&hist[key], 1);
        col[base + pos] = s;
    }
}

// ---------------- xsc[n] = (half)(x[n] * dinv[n])  [row-major fp16] ----------------
__global__ void convert_scale(const float* __restrict__ x, const float* __restrict__ dinv,
                              __half* __restrict__ xh) {
    int t = blockIdx.x * blockDim.x + threadIdx.x;
    if (t >= N_NODES * 8) return;
    const int node = t >> 3, oct = t & 7;
    const float dv = dinv[node];
    const float2* xr = (const float2*)(x + (size_t)node * 64 + oct * 8);
    __half2* xw = (__half2*)(xh + (size_t)node * 64 + oct * 8);
#pragma unroll
    for (int i = 0; i < 4; ++i) {
        const float2 v = xr[i];
        xw[i] = __floats2half2_rn(v.x * dv, v.y * dv);
    }
}

// ---------------- partial aggregation: ph[k][nd] = sum_{s in N_k(nd)} xsc[s] ------------
// k = blockIdx&3 -> each XCD gathers from ONE contiguous 3.2MB src-plane (L2-resident).
// Full-row structure: wave = (node,k), lane = feature, one 128B gather per edge.
__device__ __forceinline__ int rlane_i(int v, int l) {
    return __builtin_amdgcn_readlane(v, l);
}

__global__ __launch_bounds__(256) void agg_part(const __half* __restrict__ xh,
                                                const int* __restrict__ rowptr4,
                                                const int* __restrict__ col,
                                                __half* __restrict__ ph) {
    const int g = blockIdx.x & 7;
    const int k = g & 3;
    const int hi = g >> 2;
    const int nd = (blockIdx.x >> 3) * 8 + hi * 4 + (threadIdx.x >> 6);  // covers N exactly
    const int lane = threadIdx.x & 63;
    const int beg = rowptr4[nd * 4 + k];
    const int end = rowptr4[nd * 4 + k + 1];

    float a0 = 0.f, a1 = 0.f, a2 = 0.f, a3 = 0.f;
    for (int j = beg; j < end; j += 64) {
        const int chunk = min(end - j, 64);
        const int c = (lane < chunk) ? col[j + lane] : 0;   // coalesced 4B/lane
        int t = 0;
        for (; t + 7 < chunk; t += 8) {
            const int s0 = rlane_i(c, t + 0), s1 = rlane_i(c, t + 1);
            const int s2 = rlane_i(c, t + 2), s3 = rlane_i(c, t + 3);
            const int s4 = rlane_i(c, t + 4), s5 = rlane_i(c, t + 5);
            const int s6 = rlane_i(c, t + 6), s7 = rlane_i(c, t + 7);
            a0 += __half2float(xh[(size_t)s0 * D + lane]);
            a1 += __half2float(xh[(size_t)s1 * D + lane]);
            a2 += __half2float(xh[(size_t)s2 * D + lane]);
            a3 += __half2float(xh[(size_t)s3 * D + lane]);
            a0 += __half2float(xh[(size_t)s4 * D + lane]);
            a1 += __half2float(xh[(size_t)s5 * D + lane]);
            a2 += __half2float(xh[(size_t)s6 * D + lane]);
            a3 += __half2float(xh[(size_t)s7 * D + lane]);
        }
        for (; t < chunk; ++t) {
            const int s0 = rlane_i(c, t);
            a0 += __half2float(xh[(size_t)s0 * D + lane]);
        }
    }
    ph[(size_t)k * N_NODES * D + (size_t)nd * D + lane] =
        __float2half((a0 + a1) + (a2 + a3));
}

// ---------------- GEMM: a = dv*(sum_k ph + xsc_self); r = relu(a @ W + b) ----------------
__device__ __forceinline__ float rlane_ff(float v, int l) {
    return __int_as_float(__builtin_amdgcn_readlane(__float_as_int(v), l));
}

template <bool SCALED_HALF_OUT>
__global__ __launch_bounds__(256) void gemm64(const __half* __restrict__ ph,
                                              const __half* xh,          // may alias outh
                                              const float* __restrict__ W,
                                              const float* __restrict__ bias,
                                              const float* __restrict__ dinv,
                                              float* __restrict__ out,
                                              __half* outh, int n) {
    const int lane = threadIdx.x & 63;
    const int gwave = (blockIdx.x * blockDim.x + threadIdx.x) >> 6;
    const int nwaves = (gridDim.x * blockDim.x) >> 6;
    float wcol[64];
#pragma unroll
    for (int k = 0; k < 64; ++k) wcol[k] = W[k * 64 + lane];
    const float bv = bias[lane];

    for (int nd = gwave; nd < n; nd += nwaves) {
        const size_t off = (size_t)nd * D + lane;
        float sum = __half2float(xh[off]);            // self, UNSCALED in the sum
#pragma unroll
        for (int k = 0; k < 4; ++k)
            sum += __half2float(ph[(size_t)k * N_NODES * D + off]);
        const float a = dinv[nd] * sum;

        float g0 = 0.f, g1 = 0.f, g2 = 0.f, g3 = 0.f;
#pragma unroll
        for (int k = 0; k < 64; k += 4) {
            g0 = fmaf(rlane_ff(a, k + 0), wcol[k + 0], g0);
            g1 = fmaf(rlane_ff(a, k + 1), wcol[k + 1], g1);
            g2 = fmaf(rlane_ff(a, k + 2), wcol[k + 2], g2);
            g3 = fmaf(rlane_ff(a, k + 3), wcol[k + 3], g3);
        }
        const float r = fmaxf((g0 + g1) + (g2 + g3) + bv, 0.f);
        if (SCALED_HALF_OUT)
            outh[off] = __float2half(r * dinv[nd]);   // row-local overwrite of xh is safe:
        else                                          // only this wave reads row nd
            out[off] = r;
    }
}

extern "C" void kernel_launch(void* const* d_in, const int* in_sizes, int n_in,
                              void* d_out, int out_size, void* d_ws, size_t ws_size,
                              hipStream_t stream) {
    const float* feature = (const float*)d_in[0];
    const int*   edges   = (const int*)d_in[1];   // [2, E] flat: src then dst
    const float* W1      = (const float*)d_in[2];
    const float* b1      = (const float*)d_in[3];
    const float* W2      = (const float*)d_in[4];
    const float* b2      = (const float*)d_in[5];
    float* out = (float*)d_out;

    const int* src = edges;
    const int* dst = edges + N_EDGES;

    // workspace layout (~79MB)
    char* w = (char*)d_ws;
    int*    gcount  = (int*)w;    w += sizeof(int) * (NB * NBLK);       // 65536
    int*    subbase = (int*)w;    w += sizeof(int) * (NB * NBLK + 1);   // 65537
    int*    rowptr4 = (int*)w;    w += sizeof(int) * (4 * N_NODES + 1); // 1.6MB
    float*  dinv    = (float*)w;  w += sizeof(float) * (N_NODES);
    int*    part    = (int*)w;    w += sizeof(int) * (N_EDGES);          // 6.4MB
    int*    colA    = (int*)w;    w += sizeof(int) * (N_EDGES);          // 6.4MB
    __half* xh      = (__half*)w; w += sizeof(__half) * ((size_t)N_NODES * D);      // 12.8MB
    __half* ph      = (__half*)w; w += sizeof(__half) * ((size_t)4 * N_NODES * D);  // 51.2MB

    // ---- partition + k-sorted CSR + scaled-fp16 features (once) ----
    bucket_count<<<NBLK, 256, 0, stream>>>(dst, gcount);
    scan64k<<<1, 1024, 0, stream>>>(gcount, subbase);
    partition_edges<<<NBLK, 256, 0, stream>>>(src, dst, subbase, part);
    bucket_csr<<<NB_USED, 256, 0, stream>>>(subbase, part, colA, rowptr4, dinv);
    convert_scale<<<(N_NODES * 8 + 255) / 256, 256, 0, stream>>>(feature, dinv, xh);

    const int agg_grid = (N_NODES / 8) * 8;   // 12500 node-groups x 8 (k,half) blocks

    // ---- layer 1 (gemm overwrites xh with scaled y1) ----
    agg_part<<<agg_grid, 256, 0, stream>>>(xh, rowptr4, colA, ph);
    gemm64<true><<<2048, 256, 0, stream>>>(ph, xh, W1, b1, dinv, nullptr, xh, N_NODES);

    // ---- layer 2 ----
    agg_part<<<agg_grid, 256, 0, stream>>>(xh, rowptr4, colA, ph);
    gemm64<false><<<2048, 256, 0, stream>>>(ph, xh, W2, b2, dinv, out, nullptr, N_NODES);
}

// Round 14
// 219.069 us; speedup vs baseline: 1.7864x; 1.6444x over previous
//
#include <hip/hip_runtime.h>
#include <hip/hip_fp16.h>

#define N_NODES 100000
#define N_EDGES 1600000
#define D 64

#define NB 256                  // fat buckets
#define BUCKET_W 391            // nodes per bucket (256*391 = 100096 >= 100000)
#define NB_USED 256
#define NBLK 256                // partition blocks (exact per-block regions)
#define CHUNK ((N_EDGES + NBLK - 1) / NBLK)             // 6250
#define CCAP 7168               // max edges per bucket (mean 6250, sd ~79)
#define LMASK 511               // 9-bit local node index

// ---------------- pass A: per-block LDS histogram -> gcount[b*NBLK+blk] ----------------
__global__ __launch_bounds__(256) void bucket_count(const int* __restrict__ dst,
                                                    int* __restrict__ gcount) {
    __shared__ int h[NB];
    if (threadIdx.x < NB) h[threadIdx.x] = 0;
    __syncthreads();
    const int blk = blockIdx.x;
    const int beg = blk * CHUNK;
    const int end = min(beg + CHUNK, N_EDGES);
    for (int e = beg + threadIdx.x; e < end; e += 256)
        atomicAdd(&h[dst[e] / BUCKET_W], 1);
    __syncthreads();
    if (threadIdx.x < NB)
        gcount[threadIdx.x * NBLK + blk] = h[threadIdx.x];   // exact, no global atomics
}

// ---------------- exact scan of 65536 (bucket,block) counts -> subbase ----------------
__global__ __launch_bounds__(1024) void scan64k(const int* __restrict__ gcount,
                                                int* __restrict__ subbase) {
    __shared__ int s[1024];
    const int t = threadIdx.x;
    int loc[64];
    int sum = 0;
#pragma unroll
    for (int i = 0; i < 64; ++i) { loc[i] = gcount[t * 64 + i]; sum += loc[i]; }
    s[t] = sum;
    __syncthreads();
    for (int off = 1; off < 1024; off <<= 1) {
        int u = (t >= off) ? s[t - off] : 0;
        __syncthreads();
        s[t] += u;
        __syncthreads();
    }
    int excl = s[t] - sum;
#pragma unroll
    for (int i = 0; i < 64; ++i) { subbase[t * 64 + i] = excl; excl += loc[i]; }
    if (t == 1023) subbase[NB * NBLK] = excl;   // == N_EDGES
}

// ---------------- pass B: partition with LDS cursors (no global atomics) ----------------
__global__ __launch_bounds__(256) void partition_edges(const int* __restrict__ src,
                                                       const int* __restrict__ dst,
                                                       const int* __restrict__ subbase,
                                                       int* __restrict__ part) {
    __shared__ int cur[NB];
    const int blk = blockIdx.x;
    if (threadIdx.x < NB) cur[threadIdx.x] = subbase[threadIdx.x * NBLK + blk];
    __syncthreads();
    const int beg = blk * CHUNK;
    const int end = min(beg + CHUNK, N_EDGES);
    for (int e = beg + threadIdx.x; e < end; e += 256) {
        const int d = dst[e];
        const int s = src[e];
        const int b = d / BUCKET_W;
        const int pos = atomicAdd(&cur[b], 1);          // LDS atomic
        part[pos] = (s << 9) | (d - b * BUCKET_W);      // ~24 edges/region: lines fill
    }
}

// ---------------- pass C: per-bucket counting sort -> col, rowptr, dinv ----------------
__global__ __launch_bounds__(256) void bucket_csr(const int* __restrict__ subbase,
                                                  const int* __restrict__ part,
                                                  int* __restrict__ col,
                                                  int* __restrict__ rowptr,
                                                  float* __restrict__ dinv) {
    __shared__ int ed[CCAP];
    __shared__ int hist[BUCKET_W];
    __shared__ int offs[BUCKET_W];
    __shared__ int lcur[BUCKET_W];
    const int b = blockIdx.x;
    const int base = subbase[b * NBLK];
    const int cnt = min(subbase[(b + 1) * NBLK] - base, CCAP);
    const int n0 = b * BUCKET_W;
    const int nn = min(N_NODES - n0, BUCKET_W);
    const int t = threadIdx.x;

    for (int i = t; i < BUCKET_W; i += 256) hist[i] = 0;
    for (int i = t; i < cnt; i += 256) ed[i] = part[base + i];
    __syncthreads();
    for (int i = t; i < cnt; i += 256) atomicAdd(&hist[ed[i] & LMASK], 1);
    __syncthreads();
    if (t == 0) {
        int a = 0;
        for (int i = 0; i < nn; ++i) { offs[i] = a; lcur[i] = a; a += hist[i]; }
    }
    __syncthreads();
    for (int i = t; i < nn; i += 256) {
        rowptr[n0 + i] = base + offs[i];
        dinv[n0 + i] = rsqrtf((float)hist[i] + 1.0f);
    }
    if (b == NB_USED - 1 && t == 0) rowptr[N_NODES] = N_EDGES;
    __syncthreads();
    for (int i = t; i < cnt; i += 256) {
        const int p = ed[i];
        const int pos = atomicAdd(&lcur[p & LMASK], 1);
        col[base + pos] = p >> 9;
    }
}

// ---------------- xsc[n] = (half)(x[n] * dinv[n])  [row-major fp16] ----------------
__global__ void convert_scale(const float* __restrict__ x, const float* __restrict__ dinv,
                              __half* __restrict__ xh) {
    int t = blockIdx.x * blockDim.x + threadIdx.x;
    if (t >= N_NODES * 8) return;
    const int node = t >> 3, oct = t & 7;
    const float dv = dinv[node];
    const float2* xr = (const float2*)(x + (size_t)node * 64 + oct * 8);
    __half2* xw = (__half2*)(xh + (size_t)node * 64 + oct * 8);
#pragma unroll
    for (int i = 0; i < 4; ++i) {
        const float2 v = xr[i];
        xw[i] = __floats2half2_rn(v.x * dv, v.y * dv);
    }
}

// ---------------- aggregation, 2 nodes per wave (interleaved gather streams) -----------
// agg[d] = dv*(sum_{s in N(d)} xsc[s] + xsc[d]).  Wave owns nodes 2g, 2g+1: both col
// chunks issued up front, gather pipelines interleaved -> 2x ILP on the latency chain.
__device__ __forceinline__ int rlane_i(int v, int l) {
    return __builtin_amdgcn_readlane(v, l);
}

#define GATHER4(acc0, acc1, acc2, acc3, creg, tt)                         \
    {                                                                     \
        const int s0 = rlane_i(creg, tt + 0), s1 = rlane_i(creg, tt + 1); \
        const int s2 = rlane_i(creg, tt + 2), s3 = rlane_i(creg, tt + 3); \
        acc0 += __half2float(xh[(size_t)s0 * D + lane]);                  \
        acc1 += __half2float(xh[(size_t)s1 * D + lane]);                  \
        acc2 += __half2float(xh[(size_t)s2 * D + lane]);                  \
        acc3 += __half2float(xh[(size_t)s3 * D + lane]);                  \
    }

__global__ __launch_bounds__(256) void agg_pair(const __half* __restrict__ xh,
                                                const int* __restrict__ rowptr,
                                                const int* __restrict__ col,
                                                const float* __restrict__ dinv,
                                                __half* __restrict__ aggh, int n) {
    const int gwave = (blockIdx.x * blockDim.x + threadIdx.x) >> 6;
    const int lane = threadIdx.x & 63;
    const int nd0 = gwave * 2;
    if (nd0 >= n) return;
    const int nd1 = nd0 + 1;
    const bool has1 = nd1 < n;

    const int b0 = rowptr[nd0];
    const int e0 = rowptr[nd0 + 1];
    const int e1 = has1 ? rowptr[nd1 + 1] : e0;
    const int b1 = e0;                       // CSR rows are contiguous

    const int ch0 = min(e0 - b0, 64);
    const int ch1 = min(e1 - b1, 64);
    // both col chunks in flight before any gather
    const int c0 = (lane < ch0) ? col[b0 + lane] : 0;
    const int c1 = (lane < ch1) ? col[b1 + lane] : 0;

    float a0 = 0.f, a1 = 0.f, a2 = 0.f, a3 = 0.f;   // node0
    float d0 = 0.f, d1 = 0.f, d2 = 0.f, d3 = 0.f;   // node1

    const int m = min(ch0, ch1) & ~3;
    int t = 0;
    for (; t < m; t += 4) {                 // interleaved: 8 independent gathers in flight
        GATHER4(a0, a1, a2, a3, c0, t)
        GATHER4(d0, d1, d2, d3, c1, t)
    }
    int t0 = t, t1 = t;
    for (; t0 + 3 < ch0; t0 += 4) GATHER4(a0, a1, a2, a3, c0, t0)
    for (; t0 < ch0; ++t0) a0 += __half2float(xh[(size_t)rlane_i(c0, t0) * D + lane]);
    for (; t1 + 3 < ch1; t1 += 4) GATHER4(d0, d1, d2, d3, c1, t1)
    for (; t1 < ch1; ++t1) d0 += __half2float(xh[(size_t)rlane_i(c1, t1) * D + lane]);

    // residual chunks for degree > 64 (essentially never for Poisson(16); kept for safety)
    for (int j = b0 + 64; j < e0; j += 64) {
        const int chunk = min(e0 - j, 64);
        const int c = (lane < chunk) ? col[j + lane] : 0;
        int tt = 0;
        for (; tt + 3 < chunk; tt += 4) GATHER4(a0, a1, a2, a3, c, tt)
        for (; tt < chunk; ++tt) a0 += __half2float(xh[(size_t)rlane_i(c, tt) * D + lane]);
    }
    for (int j = b1 + 64; j < e1; j += 64) {
        const int chunk = min(e1 - j, 64);
        const int c = (lane < chunk) ? col[j + lane] : 0;
        int tt = 0;
        for (; tt + 3 < chunk; tt += 4) GATHER4(d0, d1, d2, d3, c, tt)
        for (; tt < chunk; ++tt) d0 += __half2float(xh[(size_t)rlane_i(c, tt) * D + lane]);
    }

    const float self0 = __half2float(xh[(size_t)nd0 * D + lane]);
    aggh[(size_t)nd0 * D + lane] =
        __float2half(dinv[nd0] * ((a0 + a1) + (a2 + a3) + self0));
    if (has1) {
        const float self1 = __half2float(xh[(size_t)nd1 * D + lane]);
        aggh[(size_t)nd1 * D + lane] =
            __float2half(dinv[nd1] * ((d0 + d1) + (d2 + d3) + self1));
    }
}

// ---------------- GEMM: r = relu(agg @ W + b); write fp32 or scaled-fp16 ----------------
__device__ __forceinline__ float rlane_ff(float v, int l) {
    return __int_as_float(__builtin_amdgcn_readlane(__float_as_int(v), l));
}

template <bool SCALED_HALF_OUT>
__global__ __launch_bounds__(256) void gemm64(const __half* __restrict__ aggh,
                                              const float* __restrict__ W,
                                              const float* __restrict__ bias,
                                              const float* __restrict__ dinv,
                                              float* __restrict__ out,
                                              __half* __restrict__ outh, int n) {
    const int lane = threadIdx.x & 63;
    const int gwave = (blockIdx.x * blockDim.x + threadIdx.x) >> 6;
    const int nwaves = (gridDim.x * blockDim.x) >> 6;
    float wcol[64];
#pragma unroll
    for (int k = 0; k < 64; ++k) wcol[k] = W[k * 64 + lane];
    const float bv = bias[lane];

    for (int nd = gwave; nd < n; nd += nwaves) {
        const float a = __half2float(aggh[(size_t)nd * D + lane]);
        float g0 = 0.f, g1 = 0.f, g2 = 0.f, g3 = 0.f;
#pragma unroll
        for (int k = 0; k < 64; k += 4) {
            g0 = fmaf(rlane_ff(a, k + 0), wcol[k + 0], g0);
            g1 = fmaf(rlane_ff(a, k + 1), wcol[k + 1], g1);
            g2 = fmaf(rlane_ff(a, k + 2), wcol[k + 2], g2);
            g3 = fmaf(rlane_ff(a, k + 3), wcol[k + 3], g3);
        }
        const float r = fmaxf((g0 + g1) + (g2 + g3) + bv, 0.f);
        if (SCALED_HALF_OUT)
            outh[(size_t)nd * D + lane] = __float2half(r * dinv[nd]);
        else
            out[(size_t)nd * D + lane] = r;
    }
}

extern "C" void kernel_launch(void* const* d_in, const int* in_sizes, int n_in,
                              void* d_out, int out_size, void* d_ws, size_t ws_size,
                              hipStream_t stream) {
    const float* feature = (const float*)d_in[0];
    const int*   edges   = (const int*)d_in[1];   // [2, E] flat: src then dst
    const float* W1      = (const float*)d_in[2];
    const float* b1      = (const float*)d_in[3];
    const float* W2      = (const float*)d_in[4];
    const float* b2      = (const float*)d_in[5];
    float* out = (float*)d_out;

    const int* src = edges;
    const int* dst = edges + N_EDGES;

    // workspace layout (~53MB)
    char* w = (char*)d_ws;
    int*    gcount  = (int*)w;    w += sizeof(int) * (NB * NBLK);       // 65536
    int*    subbase = (int*)w;    w += sizeof(int) * (NB * NBLK + 1);   // 65537
    int*    rowptr  = (int*)w;    w += sizeof(int) * (N_NODES + 1);
    float*  dinv    = (float*)w;  w += sizeof(float) * (N_NODES);
    int*    part    = (int*)w;    w += sizeof(int) * (N_EDGES);          // 6.4MB
    int*    colA    = (int*)w;    w += sizeof(int) * (N_EDGES);          // 6.4MB
    __half* xh      = (__half*)w; w += sizeof(__half) * ((size_t)N_NODES * D);  // 12.8MB
    __half* y1h     = (__half*)w; w += sizeof(__half) * ((size_t)N_NODES * D);  // 12.8MB
    __half* aggh    = (__half*)w; w += sizeof(__half) * ((size_t)N_NODES * D);  // 12.8MB

    // ---- partition + CSR + scaled-fp16 features (once) ----
    bucket_count<<<NBLK, 256, 0, stream>>>(dst, gcount);
    scan64k<<<1, 1024, 0, stream>>>(gcount, subbase);
    partition_edges<<<NBLK, 256, 0, stream>>>(src, dst, subbase, part);
    bucket_csr<<<NB_USED, 256, 0, stream>>>(subbase, part, colA, rowptr, dinv);
    convert_scale<<<(N_NODES * 8 + 255) / 256, 256, 0, stream>>>(feature, dinv, xh);

    const int pair_blocks = (N_NODES / 2 + 3) / 4;   // 2 nodes/wave, 4 waves/block

    // ---- layer 1 ----
    agg_pair<<<pair_blocks, 256, 0, stream>>>(xh, rowptr, colA, dinv, aggh, N_NODES);
    gemm64<true><<<2048, 256, 0, stream>>>(aggh, W1, b1, dinv, nullptr, y1h, N_NODES);

    // ---- layer 2 ----
    agg_pair<<<pair_blocks, 256, 0, stream>>>(y1h, rowptr, colA, dinv, aggh, N_NODES);
    gemm64<false><<<2048, 256, 0, stream>>>(aggh, W2, b2, dinv, out, nullptr, N_NODES);
}